// Round 11
// baseline (37.271 us; speedup 1.0000x reference)
//
#include <hip/hip_runtime.h>

#define NEG_SLOPE_F 0.2f

static constexpr int Nn = 4096;   // nodes
static constexpr int Tt = 3;      // edge types
static constexpr int Dd = 16;     // emb dim
static constexpr int Hh = 4;      // heads
static constexpr int CAP = 256;   // per-row segment capacity (E[inserts/row]=96, 16 sigma)
static constexpr int NB = 128;    // binning blocks

__device__ __forceinline__ float waveMax(float v) {
#pragma unroll
  for (int m = 1; m < 64; m <<= 1) v = fmaxf(v, __shfl_xor(v, m));
  return v;
}
__device__ __forceinline__ float waveSum(float v) {
#pragma unroll
  for (int m = 1; m < 64; m <<= 1) v += __shfl_xor(v, m);
  return v;
}

// ---- K1: per-block LDS histogram of endpoint-rows -> ghist[b][r] ----
__global__ void hist_kernel(const int* __restrict__ el,
                            unsigned int* __restrict__ ghist, int E) {
  __shared__ unsigned int lh[Nn];  // 16 KB
  int tid = threadIdx.x, b = blockIdx.x;
  for (int r = tid; r < Nn; r += 256) lh[r] = 0u;
  __syncthreads();
  int nE = Tt * E;
  int per = (nE + NB - 1) / NB;
  int k0 = b * per, k1 = k0 + per;
  if (k1 > nE) k1 = nE;
  for (int k = k0 + tid; k < k1; k += 256) {
    int t = k / E, e = k - t * E;
    unsigned int a = (unsigned int)el[(t * 2 + 0) * E + e];
    unsigned int c = (unsigned int)el[(t * 2 + 1) * E + e];
    atomicAdd(&lh[a], 1u);
    atomicAdd(&lh[c], 1u);
  }
  __syncthreads();
  unsigned int* gh = ghist + (size_t)b * Nn;
  for (int r = tid; r < Nn; r += 256) gh[r] = lh[r];  // coalesced
}

// ---- K2: per-row exclusive scan across 128 block-counts -> ofs[b][r];
// block 0 additionally computes pv[0..11]=c[h][t], pv[12]=sum(scores) ----
__global__ void scan_prep_kernel(const unsigned int* __restrict__ ghist,
                                 unsigned int* __restrict__ ofs,
                                 unsigned int* __restrict__ cnt,
                                 const float* __restrict__ scores,
                                 const float* __restrict__ emb,
                                 const float* __restrict__ attw,
                                 float* __restrict__ pv) {
  if (blockIdx.x == 0) {
    __shared__ float rb[4];
    int tid = threadIdx.x;
    float s = 0.f;
    for (int j = tid; j < Nn; j += 256) s += scores[j];
    s = waveSum(s);
    if ((tid & 63) == 0) rb[tid >> 6] = s;
    __syncthreads();
    if (tid == 0) pv[12] = rb[0] + rb[1] + rb[2] + rb[3];
    if (tid < Hh * Tt) {
      int h = tid / Tt, t = tid % Tt;
      float c = 0.f;
#pragma unroll
      for (int d = 0; d < Dd; ++d)
        c += emb[t * Dd + d] * attw[h * (Dd + 2) + 1 + d];
      pv[tid] = c;
    }
  }
  int wid = threadIdx.x >> 6, lane = threadIdx.x & 63;
  int r = blockIdx.x * 4 + wid;
  // lane holds block-columns 2*lane and 2*lane+1 of row r
  unsigned int a = ghist[(size_t)(2 * lane) * Nn + r];
  unsigned int c = ghist[(size_t)(2 * lane + 1) * Nn + r];
  unsigned int s = a + c;
  unsigned int inc = s;
#pragma unroll
  for (int d = 1; d < 64; d <<= 1) {
    unsigned int tv = __shfl_up(inc, d);
    if (lane >= d) inc += tv;
  }
  unsigned int excl = inc - s;
  unsigned int base = (unsigned int)r * CAP;
  ofs[(size_t)(2 * lane) * Nn + r] = base + excl;
  ofs[(size_t)(2 * lane + 1) * Nn + r] = base + excl + a;
  if (lane == 63) cnt[r] = inc;  // total inserts (with duplicates)
}

// ---- K3: scatter entries into per-row segments; slot allocation via LDS
// atomicAdd on the block's private offset array (no global atomics) ----
__global__ void scatter_kernel(const int* __restrict__ el,
                               const unsigned int* __restrict__ ofs,
                               unsigned short* __restrict__ seg, int E) {
  __shared__ unsigned int lofs[Nn];  // 16 KB
  int tid = threadIdx.x, b = blockIdx.x;
  const unsigned int* ob = ofs + (size_t)b * Nn;
  for (int r = tid; r < Nn; r += 256) lofs[r] = ob[r];  // coalesced
  __syncthreads();
  int nE = Tt * E;
  int per = (nE + NB - 1) / NB;
  int k0 = b * per, k1 = k0 + per;
  if (k1 > nE) k1 = nE;
  for (int k = k0 + tid; k < k1; k += 256) {
    int t = k / E, e = k - t * E;
    unsigned int a = (unsigned int)el[(t * 2 + 0) * E + e];
    unsigned int c = (unsigned int)el[(t * 2 + 1) * E + e];
    unsigned int pa = atomicAdd(&lofs[a], 1u);
    if (pa - a * (unsigned)CAP < (unsigned)CAP)
      seg[pa] = (unsigned short)(c | ((unsigned)t << 12));
    unsigned int pc = atomicAdd(&lofs[c], 1u);
    if (pc - c * (unsigned)CAP < (unsigned)CAP)
      seg[pc] = (unsigned short)(a | ((unsigned)t << 12));
  }
}

// ---- K4: one wave per row — LDS-bitmap dedup of the row's segment, then
// canonical extraction + analytic sparse softmax (proven path) ----
__launch_bounds__(256)
__global__ void row_kernel(const unsigned short* __restrict__ seg,
                           const unsigned int* __restrict__ cnt,
                           const float* __restrict__ scores,
                           const float* __restrict__ attw,
                           const float* __restrict__ pv,
                           float* __restrict__ out) {
  __shared__ unsigned int bmL[4][Tt * 128];   // 6 KB, wave-private slices
  __shared__ unsigned short lst[4][CAP];      // 2 KB, wave-private slices
  int wid = threadIdx.x >> 6, lane = threadIdx.x & 63;
  int i = blockIdx.x * 4 + wid;
  unsigned int* bm = bmL[wid];

  for (int q = lane; q < Tt * 128; q += 64) bm[q] = 0u;
  int nd = (int)cnt[i];
  if (nd > CAP) nd = CAP;
  const unsigned short* sg = seg + (size_t)i * CAP;
  for (int k = lane; k < nd; k += 64) {
    unsigned int v = (unsigned int)sg[k];
    unsigned int col = v & 0xFFFu, t = v >> 12;
    atomicOr(&bm[t * 128 + (col >> 5)], 1u << (col & 31u));  // LDS, same wave
  }
  // same-wave LDS ops are processed in order; no block barrier needed.

  unsigned int w[2][3];
#pragma unroll
  for (int p = 0; p < 2; ++p)
#pragma unroll
    for (int t = 0; t < 3; ++t) w[p][t] = bm[t * 128 + p * 64 + lane];
  unsigned int orw[2];
  orw[0] = w[0][0] | w[0][1] | w[0][2];
  orw[1] = w[1][0] | w[1][1] | w[1][2];
  int c = __popc(orw[0]) + __popc(orw[1]);
  int off = c;
#pragma unroll
  for (int d = 1; d < 64; d <<= 1) {
    int tv = __shfl_up(off, d);
    if (lane >= d) off += tv;
  }
  int n = __shfl(off, 63);  // distinct neighbors
  off -= c;                 // exclusive
  if (n > CAP) n = CAP;
  int idx = off;
#pragma unroll
  for (int p = 0; p < 2; ++p) {
    unsigned int o = orw[p];
    int jbase = (p * 64 + lane) * 32;
    while (o) {
      int b = __ffs(o) - 1;
      o &= o - 1;
      unsigned int m = ((w[p][0] >> b) & 1u) | (((w[p][1] >> b) & 1u) << 1) |
                       (((w[p][2] >> b) & 1u) << 2);
      if (idx < CAP) lst[wid][idx] = (unsigned short)((jbase + b) | (m << 12));
      ++idx;
    }
  }

  float si = scores[i];
  float wsrc[Hh], wtgt[Hh], c0[Hh], c1[Hh], c2[Hh];
#pragma unroll
  for (int h = 0; h < Hh; ++h) {
    wsrc[h] = attw[h * (Dd + 2) + 0];
    wtgt[h] = attw[h * (Dd + 2) + Dd + 1];
    c0[h] = pv[h * 3 + 0];
    c1[h] = pv[h * 3 + 1];
    c2[h] = pv[h * 3 + 2];
  }
  float Ssum = pv[12];

  constexpr int IT = CAP / 64;  // 4
  float lv[IT][Hh], sjv[IT];
  float mx[Hh];
#pragma unroll
  for (int h = 0; h < Hh; ++h) mx[h] = -INFINITY;
  float sedge = 0.f;

#pragma unroll
  for (int it = 0; it < IT; ++it) {
    if (it * 64 >= n) break;  // wave-uniform early-out
    int k = it * 64 + lane;
    bool act = k < n;
    unsigned int v = act ? (unsigned int)lst[wid][k] : 0u;
    int j = (int)(v & 0xFFFu);
    int m = act ? (int)(v >> 12) : 0;
    float sj = act ? scores[j] : 0.f;
    sjv[it] = sj;
    if (act) sedge += sj;
    float na = (float)__popc(m);
    float et0 = (m & 1) ? 1.f : 0.f;
    float et1 = (m & 2) ? 1.f : 0.f;
    float et2 = (m & 4) ? 1.f : 0.f;
#pragma unroll
    for (int h = 0; h < Hh; ++h) {
      float et = et0 * c0[h] + et1 * c1[h] + et2 * c2[h];
      float l = na * (wsrc[h] * si + wtgt[h] * sj) + et;
      l = (l >= 0.f) ? l : NEG_SLOPE_F * l;
      lv[it][h] = act ? l : -INFINITY;
      mx[h] = fmaxf(mx[h], lv[it][h]);
    }
  }

#pragma unroll
  for (int h = 0; h < Hh; ++h) {
    mx[h] = waveMax(mx[h]);
    if (n < Nn) mx[h] = fmaxf(mx[h], 0.f);  // non-edge cells contribute logit 0
  }

  float se[Hh], ss[Hh];
#pragma unroll
  for (int h = 0; h < Hh; ++h) { se[h] = 0.f; ss[h] = 0.f; }
#pragma unroll
  for (int it = 0; it < IT; ++it) {
    if (it * 64 >= n) break;
#pragma unroll
    for (int h = 0; h < Hh; ++h) {
      float ex = expf(lv[it][h] - mx[h]);  // inactive lanes: exp(-inf)=0
      se[h] += ex;
      ss[h] += ex * sjv[it];
    }
  }
  sedge = waveSum(sedge);
#pragma unroll
  for (int h = 0; h < Hh; ++h) {
    se[h] = waveSum(se[h]);
    ss[h] = waveSum(ss[h]);
  }
  if (lane == 0) {
    float acc = 0.f;
#pragma unroll
    for (int h = 0; h < Hh; ++h) {
      float nz = expf(-mx[h]);  // exp(0 - max) for every non-edge cell
      float denom = se[h] + nz * ((float)Nn - (float)n);
      float numer = ss[h] + nz * (Ssum - sedge);
      acc += numer / denom;
    }
    out[i] = acc * (1.f / (float)Hh);
  }
}

extern "C" void kernel_launch(void* const* d_in, const int* in_sizes, int n_in,
                              void* d_out, int out_size, void* d_ws, size_t ws_size,
                              hipStream_t stream) {
  const float* scores = (const float*)d_in[0];
  const float* emb    = (const float*)d_in[1];
  const float* attw   = (const float*)d_in[2];
  const int*   el     = (const int*)d_in[3];
  float* out = (float*)d_out;
  int E = in_sizes[3] / (Tt * 2);

  // ws layout: [ghist 2MB][ofs 2MB][cnt 16KB][pv 64B][seg 2MB]
  unsigned int* ghist = (unsigned int*)d_ws;
  unsigned int* ofs = ghist + (size_t)NB * Nn;
  unsigned int* cnt = ofs + (size_t)NB * Nn;
  float* pv = (float*)(cnt + Nn);
  unsigned short* seg = (unsigned short*)((char*)pv + 64);

  hist_kernel<<<NB, 256, 0, stream>>>(el, ghist, E);
  scan_prep_kernel<<<Nn / 4, 256, 0, stream>>>(ghist, ofs, cnt, scores, emb,
                                               attw, pv);
  scatter_kernel<<<NB, 256, 0, stream>>>(el, ofs, seg, E);
  row_kernel<<<Nn / 4, 256, 0, stream>>>(seg, cnt, scores, attw, pv, out);
}